// Round 1
// baseline (46.265 us; speedup 1.0000x reference)
//
#include <hip/hip_runtime.h>
#include <hip/hip_bf16.h>

// SCC: out[b,o,h,w] = sum_{j=0..7} w[o,j] * x[b, (o*4 + j) % 64, h, w]
// B=32, C_IN=C_OUT=64, H=W=128, G=8, STEP=4. All float32.
//
// Strategy: one thread = one spatial pixel (b,h,w). Load all 64 input
// channel values for that pixel into registers (coalesced: consecutive
// lanes -> consecutive w), then compute all 64 outputs with fully
// unrolled static indexing. Each x value is reused 8x from registers,
// so HBM traffic is the 128 MiB read + 128 MiB write minimum.

#define CIN   64
#define COUT  64
#define GW    8
#define STEP  4
#define HW    (128 * 128)

__global__ __launch_bounds__(256) void scc_kernel(
    const float* __restrict__ x,
    const float* __restrict__ w,
    float* __restrict__ out,
    int total_pixels)
{
    __shared__ float ws[COUT * GW];
    for (int i = threadIdx.x; i < COUT * GW; i += blockDim.x)
        ws[i] = w[i];
    __syncthreads();

    int p = blockIdx.x * blockDim.x + threadIdx.x;   // pixel id in [0, B*HW)
    if (p >= total_pixels) return;

    int b  = p >> 14;          // p / HW   (HW = 16384 = 2^14)
    int hw = p & (HW - 1);     // p % HW

    const float* xp = x + ((long)b * CIN) * HW + hw;
    float* op       = out + ((long)b * COUT) * HW + hw;

    // Load all 64 channels for this pixel into registers.
    float xv[CIN];
#pragma unroll
    for (int c = 0; c < CIN; ++c)
        xv[c] = xp[(long)c * HW];

    // Compute all 64 output channels; indices are compile-time constants.
#pragma unroll
    for (int o = 0; o < COUT; ++o) {
        float acc = 0.0f;
#pragma unroll
        for (int j = 0; j < GW; ++j)
            acc = fmaf(ws[o * GW + j], xv[(o * STEP + j) & (CIN - 1)], acc);
        op[(long)o * HW] = acc;
    }
}

extern "C" void kernel_launch(void* const* d_in, const int* in_sizes, int n_in,
                              void* d_out, int out_size, void* d_ws, size_t ws_size,
                              hipStream_t stream) {
    const float* x = (const float*)d_in[0];
    const float* w = (const float*)d_in[1];
    float* out     = (float*)d_out;

    const int total_pixels = 32 * HW;   // B * H * W = 524288
    const int block = 256;
    const int grid  = (total_pixels + block - 1) / block;   // 2048

    scc_kernel<<<grid, block, 0, stream>>>(x, w, out, total_pixels);
}